// Round 8
// baseline (233.389 us; speedup 1.0000x reference)
//
#include <hip/hip_runtime.h>
#include <math.h>

#define HH 256
#define WW 256
#define HW (HH*WW)
#define NPX (2*HW)          // 131072 pixels total

typedef __attribute__((ext_vector_type(8))) short bf16x8;
typedef __attribute__((ext_vector_type(8))) _Float16 f16x8;
typedef __attribute__((ext_vector_type(4))) _Float16 f16x4;
typedef __attribute__((ext_vector_type(2))) _Float16 f16x2;
typedef __attribute__((ext_vector_type(4))) float f32x4;

__device__ __forceinline__ float bf2f(short h) {
    union { unsigned u; float f; } v; v.u = ((unsigned)(unsigned short)h) << 16; return v.f;
}
__device__ __forceinline__ short f2bf(float f) {        // RNE
    union { float f; unsigned u; } v; v.f = f;
    unsigned r = v.u + 0x7fffu + ((v.u >> 16) & 1u);
    return (short)(r >> 16);
}
__device__ __forceinline__ short f2hs(float f) {        // f32 -> fp16 bits
    _Float16 h = (_Float16)f;
    union { _Float16 h; short s; } v; v.h = h; return v.s;
}

// ---------- x NCHW fp32 -> channel-last fp16 + weight prep ----------
__global__ __launch_bounds__(256) void k_x2cl(const float* __restrict__ x,
        short* __restrict__ xcl,
        const float* __restrict__ w_om, const float* __restrict__ w_dcn,
        const float* __restrict__ w_h,  const float* __restrict__ w_w,
        const float* __restrict__ w3,
        short* __restrict__ wt_om, short* __restrict__ wt_dcn,
        short* __restrict__ wt_h,  short* __restrict__ wt_w,
        float* __restrict__ w3t) {
    __shared__ short tile[256 * 70];                 // 35,840 B
    const int xx = threadIdx.x;
    const int row = blockIdx.x;               // b*256 + y
    const int b = row >> 8, y = row & 255;
#pragma unroll 8
    for (int c = 0; c < 64; ++c)
        tile[xx * 70 + c] = f2hs(x[((size_t)(b * 64 + c) << 16) + (y << 8) + xx]);
    int i = blockIdx.x * 256 + threadIdx.x;
    if (i < 64 * 576) {
        int o = i / 576, k = i - o * 576, t = k >> 6, c = k & 63;
        int kb = k >> 3, j = k & 7;
        int src = (o * 64 + c) * 9 + t;
        int dst = (kb * 64 + o) * 8 + j;
        wt_dcn[dst] = f2hs(w_dcn[src]);
        wt_h[dst]   = f2bf(w_h[src]);
        wt_w[dst]   = f2bf(w_w[src]);
        if (o < 32) wt_om[(kb * 32 + o) * 8 + j] = (o < 27) ? f2hs(w_om[src]) : (short)0;
        if (o == 0) w3t[k] = w3[c * 9 + t];
    }
    __syncthreads();
    short* op = xcl + ((row << 8) + xx) * 64;
    const int* tp = (const int*)&tile[xx * 70];      // 4B-aligned (140B row stride)
#pragma unroll
    for (int j = 0; j < 8; ++j) {
        int4 v;
        v.x = tp[j * 4 + 0]; v.y = tp[j * 4 + 1];
        v.z = tp[j * 4 + 2]; v.w = tp[j * 4 + 3];
        *(int4*)(op + j * 8) = v;                    // 16B coalesced store
    }
}

#define XPS 72   // LDS pixel stride (shorts): 144B, 16B-aligned

// ---------- FUSED om-conv + modulated deformable conv + BN1 + ReLU ----------
__global__ __launch_bounds__(256) __attribute__((amdgpu_waves_per_eu(2, 4)))
void k_dcn_mfma(const short* __restrict__ xcl,
        const short* __restrict__ wom, const float* __restrict__ b_om,
        const short* __restrict__ wt,
        const float* __restrict__ bias,
        const float* __restrict__ gg, const float* __restrict__ be,
        const float* __restrict__ mu, const float* __restrict__ var,
        short* __restrict__ out_cl) {
    __shared__ short xt[256 * XPS];                 // 36,864 B
    __shared__ _Float16 om_lds[64 * 32];            //  4,096 B
    const int lane = threadIdx.x & 63, wave = threadIdx.x >> 6;
    const int quad = lane >> 4, l16 = lane & 15;
    const int band = blockIdx.x & 7, idx = blockIdx.x >> 3;
    const int tr = band * 8 + (idx >> 5), tc = idx & 31;
    const int b = tr >> 5;
    const int ty0 = (tr & 31) * 8, tx0 = tc * 8;
    const int base = b << 16;
    const int hy0 = ty0 - 4, hx0 = tx0 - 4;
    // ---- stage 16x16 halo (clamped) ----
    {
        const int p = threadIdx.x;
        const int sy = min(max(hy0 + (p >> 4), 0), 255);
        const int sx = min(max(hx0 + (p & 15), 0), 255);
        const short* src = xcl + (size_t)((base + sy * 256 + sx) * 64);
        short* dst = &xt[p * XPS];
#pragma unroll
        for (int j = 0; j < 8; ++j)
            *(bf16x8*)(dst + j * 8) = *(const bf16x8*)(src + j * 8);
    }
    __syncthreads();

    const int lp = wave * 16 + l16;        // tile-local pixel (A-row m=l16)
    const int pyy = lp >> 3, pxx = lp & 7;
    const int y = ty0 + pyy, x = tx0 + pxx;

    // ---- phase 1: om conv for this tile (zero-OOB taps) ----
    {
        f32x4 oacc[2];
        oacc[0] = (f32x4){0,0,0,0}; oacc[1] = (f32x4){0,0,0,0};
        auto loadOB = [&](int s, f16x8* Bv) {
            const int kb = s * 4 + quad;
#pragma unroll
            for (int g = 0; g < 2; ++g)
                Bv[g] = *(const f16x8*)(wom + (kb * 32 + g * 16 + l16) * 8);
        };
        f16x8 OB[2][2];
        loadOB(0, OB[0]);
#pragma unroll
        for (int s = 0; s < 18; ++s) {
            if (s < 17) loadOB(s + 1, OB[(s + 1) & 1]);
            const int t = s >> 1, c0 = (s & 1) * 32;
            const int dy = t / 3 - 1, dx = t % 3 - 1;
            f16x8 av = *(const f16x8*)&xt[((pyy + 4 + dy) * 16 + (pxx + 4 + dx)) * XPS + c0 + quad * 8];
            bool ok = ((unsigned)(y + dy) < 256u) && ((unsigned)(x + dx) < 256u);
            if (!ok) { f16x8 z = {0,0,0,0,0,0,0,0}; av = z; }
#pragma unroll
            for (int g = 0; g < 2; ++g)
                oacc[g] = __builtin_amdgcn_mfma_f32_16x16x32_f16(av, OB[s & 1][g], oacc[g], 0, 0, 0);
        }
#pragma unroll
        for (int g = 0; g < 2; ++g) {
            int o = g * 16 + l16;
            if (o < 27) {
                float bo = b_om[o];
#pragma unroll
                for (int r = 0; r < 4; ++r) {
                    float v = oacc[g][r] + bo;
                    if (o >= 18) v = 1.f / (1.f + expf(-v));     // sigmoid(mask)
                    om_lds[(wave * 16 + quad * 4 + r) * 32 + o] = (_Float16)v;
                }
            }
        }
    }
    __syncthreads();

    // ---- phase 2: deformable conv, branchless, all-LDS gather, B double-buffer ----
    f32x4 acc[4];
#pragma unroll
    for (int i = 0; i < 4; ++i) acc[i] = (f32x4){0,0,0,0};

    _Float16 omh[28];
    *(f16x8*)&omh[0]  = *(const f16x8*)&om_lds[lp * 32];
    *(f16x8*)&omh[8]  = *(const f16x8*)&om_lds[lp * 32 + 8];
    *(f16x8*)&omh[16] = *(const f16x8*)&om_lds[lp * 32 + 16];
    *(f16x4*)&omh[24] = *(const f16x4*)&om_lds[lp * 32 + 24];

    f16x8 BR0[2][4], BR1[2][4];
    auto loadBt = [&](int t, f16x8 B[2][4]) {
#pragma unroll
        for (int h = 0; h < 2; ++h) {
            const int kb = t * 8 + h * 4 + quad;
#pragma unroll
            for (int g = 0; g < 4; ++g)
                B[h][g] = *(const f16x8*)(wt + (kb * 64 + g * 16 + l16) * 8);
        }
    };
    loadBt(0, BR0);

#pragma unroll
    for (int t = 0; t < 9; ++t) {
        f16x8 (*Bc)[4] = (t & 1) ? BR1 : BR0;
        f16x8 (*Bn)[4] = (t & 1) ? BR0 : BR1;
        if (t < 8) loadBt(t + 1, Bn);

        const int ky = t / 3 - 1, kx = t % 3 - 1;
        float o1 = (float)omh[t], o2 = (float)omh[9 + t], m = (float)omh[18 + t];
        float py = (float)(y + ky) + o1;
        float px = (float)(x + kx) + o2;
        float y0f = floorf(py), x0f = floorf(px);
        float wy1 = py - y0f, wx1 = px - x0f;
        int y0 = (int)y0f, xi0 = (int)x0f, y1 = y0 + 1, xi1 = xi0 + 1;
        float w00 = (1.f - wy1) * (1.f - wx1) * m;
        float w01 = (1.f - wy1) * wx1 * m;
        float w10 = wy1 * (1.f - wx1) * m;
        float w11 = wy1 * wx1 * m;
        if (!((unsigned)y0  < 256u)) { w00 = 0.f; w01 = 0.f; }
        if (!((unsigned)y1  < 256u)) { w10 = 0.f; w11 = 0.f; }
        if (!((unsigned)xi0 < 256u)) { w00 = 0.f; w10 = 0.f; }
        if (!((unsigned)xi1 < 256u)) { w01 = 0.f; w11 = 0.f; }
        int cy0 = min(max(y0, 0), 255), cy1 = min(max(y1, 0), 255);
        int cx0 = min(max(xi0, 0), 255), cx1 = min(max(xi1, 0), 255);
        int iy0 = cy0 - hy0, iy1 = cy1 - hy0;
        int ix0 = cx0 - hx0, ix1 = cx1 - hx0;
        if (!((unsigned)iy0 < 16u)) { w00 = 0.f; w01 = 0.f; iy0 = min(max(iy0, 0), 15); }
        if (!((unsigned)iy1 < 16u)) { w10 = 0.f; w11 = 0.f; iy1 = min(max(iy1, 0), 15); }
        if (!((unsigned)ix0 < 16u)) { w00 = 0.f; w10 = 0.f; ix0 = min(max(ix0, 0), 15); }
        if (!((unsigned)ix1 < 16u)) { w01 = 0.f; w11 = 0.f; ix1 = min(max(ix1, 0), 15); }

        const int p00 = (iy0 * 16 + ix0) * XPS, p01 = (iy0 * 16 + ix1) * XPS;
        const int p10 = (iy1 * 16 + ix0) * XPS, p11 = (iy1 * 16 + ix1) * XPS;
        f16x8 C[2][4];
#pragma unroll
        for (int h = 0; h < 2; ++h) {
            const int cb = h * 32 + quad * 8;
            C[h][0] = *(const f16x8*)&xt[p00 + cb];
            C[h][1] = *(const f16x8*)&xt[p01 + cb];
            C[h][2] = *(const f16x8*)&xt[p10 + cb];
            C[h][3] = *(const f16x8*)&xt[p11 + cb];
        }
        const _Float16 h00 = (_Float16)w00, h01 = (_Float16)w01;
        const _Float16 h10 = (_Float16)w10, h11 = (_Float16)w11;
        const f16x2 W00 = {h00, h00}, W01 = {h01, h01};
        const f16x2 W10 = {h10, h10}, W11 = {h11, h11};
#pragma unroll
        for (int h = 0; h < 2; ++h) {
            const f16x2* c0 = (const f16x2*)&C[h][0];
            const f16x2* c1 = (const f16x2*)&C[h][1];
            const f16x2* c2 = (const f16x2*)&C[h][2];
            const f16x2* c3 = (const f16x2*)&C[h][3];
            f16x8 av;
            f16x2* avp = (f16x2*)&av;
#pragma unroll
            for (int d = 0; d < 4; ++d) {
                f16x2 s = c0[d] * W00;
                s = __builtin_elementwise_fma(c1[d], W01, s);
                s = __builtin_elementwise_fma(c2[d], W10, s);
                s = __builtin_elementwise_fma(c3[d], W11, s);
                avp[d] = s;
            }
#pragma unroll
            for (int g = 0; g < 4; ++g)
                acc[g] = __builtin_amdgcn_mfma_f32_16x16x32_f16(av, Bc[h][g], acc[g], 0, 0, 0);
        }
    }
#pragma unroll
    for (int g = 0; g < 4; ++g) {
        int o = g * 16 + l16;
        float sc = gg[o] * rsqrtf(var[o] + 1e-5f);
        float off = (bias[o] - mu[o]) * sc + be[o];
#pragma unroll
        for (int r = 0; r < 4; ++r) {
            int mm = quad * 4 + r;
            int pix = base + ((ty0 + wave * 2 + (mm >> 3)) << 8) + tx0 + (mm & 7);
            float v = acc[g][r] * sc + off;
            out_cl[(size_t)pix * 64 + o] = f2bf(fmaxf(v, 0.f));
        }
    }
}

// ---------- dilated conv (dil=2 pad=2): NO LDS — direct coalesced global A-reads ----------
// A-access is regular (1KB dense per wave-load, L2-resident per XCD band);
// full unroll lets the compiler deep-pipeline loads under vmcnt. No barrier, no LDS cap.
__global__ __launch_bounds__(512)
void k_conv_mfma(const short* __restrict__ in_cl,
        const short* __restrict__ wt, const float* __restrict__ bias,
        const float* __restrict__ gg, const float* __restrict__ be,
        const float* __restrict__ mu, const float* __restrict__ var,
        short* __restrict__ out_cl) {
    const int lane = threadIdx.x & 63, wave = threadIdx.x >> 6;   // wave 0..7
    const int quad = lane >> 4, l16 = lane & 15;
    const int tIdx = ((int)blockIdx.x & 7) * 64 + ((int)blockIdx.x >> 3);   // 512 blocks
    const int tr = tIdx >> 4, tc = tIdx & 15;
    const int b = tr >> 4;
    const int ty0 = (tr & 15) * 16, tx0 = tc * 16;
    const int base = b << 16;
    const int row0 = ty0 + wave * 2;          // this wave's output rows: row0, row0+1
    const int sx0 = tx0 + l16;

    f32x4 acc[2][4];
#pragma unroll
    for (int h = 0; h < 2; ++h)
#pragma unroll
        for (int g = 0; g < 4; ++g) acc[h][g] = (f32x4){0,0,0,0};

    auto loadB = [&](int s, bf16x8* Bv) {
        const int kb = s * 4 + quad;
#pragma unroll
        for (int g = 0; g < 4; ++g)
            Bv[g] = *(const bf16x8*)(wt + (kb * 64 + g * 16 + l16) * 8);
    };
    bf16x8 B[3][4];
    loadB(0, B[0]);
    loadB(1, B[1]);
#pragma unroll
    for (int s = 0; s < 18; ++s) {
        if (s + 2 < 18) loadB(s + 2, B[(s + 2) % 3]);
        const int t = s >> 1, c0 = (s & 1) * 32;
        const int dy = (t / 3 - 1) * 2, dx = (t % 3 - 1) * 2;
        const int cb = c0 + quad * 8;
        const int sy0 = row0 + dy, sy1 = sy0 + 1;
        const int sx = sx0 + dx;
        const int cx = min(max(sx, 0), 255);
        const int cy0 = min(max(sy0, 0), 255), cy1 = min(max(sy1, 0), 255);
        bf16x8 a0 = *(const bf16x8*)(in_cl + (size_t)((base + cy0 * 256 + cx) * 64 + cb));
        bf16x8 a1 = *(const bf16x8*)(in_cl + (size_t)((base + cy1 * 256 + cx) * 64 + cb));
        const bool okx = ((unsigned)sx < 256u);
        const bf16x8 z = {0,0,0,0,0,0,0,0};
        if (!(okx && ((unsigned)sy0 < 256u))) a0 = z;
        if (!(okx && ((unsigned)sy1 < 256u))) a1 = z;
#pragma unroll
        for (int g = 0; g < 4; ++g) {
            acc[0][g] = __builtin_amdgcn_mfma_f32_16x16x32_bf16(a0, B[s % 3][g], acc[0][g], 0, 0, 0);
            acc[1][g] = __builtin_amdgcn_mfma_f32_16x16x32_bf16(a1, B[s % 3][g], acc[1][g], 0, 0, 0);
        }
    }
#pragma unroll
    for (int h = 0; h < 2; ++h)
#pragma unroll
    for (int g = 0; g < 4; ++g) {
        int o = g * 16 + l16;
        float sc = gg[o] * rsqrtf(var[o] + 1e-5f);
        float off = (bias[o] - mu[o]) * sc + be[o];
#pragma unroll
        for (int r = 0; r < 4; ++r) {
            int pix = base + ((ty0 + wave * 2 + h) << 8) + tx0 + quad * 4 + r;
            float v = acc[h][g][r] * sc + off;
            out_cl[(size_t)pix * 64 + o] = f2bf(fmaxf(v, 0.f));
        }
    }
}

// ---------- final 3x3 conv (pad=1) + sigmoid + clip : 16x16 tile + 18x18 halo ----------
__global__ __launch_bounds__(256) void k_final(const short* __restrict__ h_cl,
        const float* __restrict__ w3t, const float* __restrict__ b3,
        float* __restrict__ out) {
    __shared__ short xt[324 * XPS];                  // 46.7 KB
    const int tIdx = (blockIdx.x & 7) * 64 + (blockIdx.x >> 3);   // 512 blocks
    const int tr = tIdx >> 4, tc = tIdx & 15;
    const int b = tr >> 4;
    const int ty0 = (tr & 15) * 16, tx0 = tc * 16;
    const int base = b << 16;
    for (int i = threadIdx.x; i < 324 * 8; i += 256) {
        const int p = i >> 3, j = i & 7;
        const int sy = ty0 - 1 + p / 18, sx = tx0 - 1 + p % 18;
        bf16x8 v = {0,0,0,0,0,0,0,0};
        if (((unsigned)sy < 256u) && ((unsigned)sx < 256u))
            v = *(const bf16x8*)(h_cl + (size_t)((base + sy * 256 + sx) * 64 + j * 8));
        *(bf16x8*)(&xt[p * XPS + j * 8]) = v;
    }
    __syncthreads();
    const int ly = threadIdx.x >> 4, lx = threadIdx.x & 15;
    float a0 = 0.f, a1 = 0.f, a2 = 0.f, a3 = 0.f;
#pragma unroll
    for (int t = 0; t < 9; ++t) {
        const int hidx = (ly + 1 + t / 3 - 1) * 18 + (lx + 1 + t % 3 - 1);
        const short* hp = &xt[hidx * XPS];
        const float* wp = w3t + t * 64;
#pragma unroll
        for (int j = 0; j < 64; j += 32) {
            bf16x8 v0 = *(const bf16x8*)(hp + j);
            bf16x8 v1 = *(const bf16x8*)(hp + j + 8);
            bf16x8 v2 = *(const bf16x8*)(hp + j + 16);
            bf16x8 v3 = *(const bf16x8*)(hp + j + 24);
#pragma unroll
            for (int e = 0; e < 8; ++e) {
                a0 = fmaf(bf2f(v0[e]), wp[j + e], a0);
                a1 = fmaf(bf2f(v1[e]), wp[j + 8 + e], a1);
                a2 = fmaf(bf2f(v2[e]), wp[j + 16 + e], a2);
                a3 = fmaf(bf2f(v3[e]), wp[j + 24 + e], a3);
            }
        }
    }
    float acc = (a0 + a1) + (a2 + a3);
    float s = 1.f / (1.f + expf(-(acc + b3[0])));
    out[base + ((ty0 + ly) << 8) + tx0 + lx] = fminf(fmaxf(s, 1e-4f), 1.f - 1e-4f);
}

extern "C" void kernel_launch(void* const* d_in, const int* in_sizes, int n_in,
                              void* d_out, int out_size, void* d_ws, size_t ws_size,
                              hipStream_t stream) {
    const float* x     = (const float*)d_in[0];
    const float* w_om  = (const float*)d_in[1];
    const float* b_om  = (const float*)d_in[2];
    const float* w_dcn = (const float*)d_in[3];
    const float* b_dcn = (const float*)d_in[4];
    const float* bn1g = (const float*)d_in[5],  *bn1b = (const float*)d_in[6];
    const float* bn1m = (const float*)d_in[7],  *bn1v = (const float*)d_in[8];
    const float* bn2g = (const float*)d_in[9],  *bn2b = (const float*)d_in[10];
    const float* bn2m = (const float*)d_in[11], *bn2v = (const float*)d_in[12];
    const float* bn3g = (const float*)d_in[13], *bn3b = (const float*)d_in[14];
    const float* bn3m = (const float*)d_in[15], *bn3v = (const float*)d_in[16];
    const float* w_h = (const float*)d_in[17], *b_h = (const float*)d_in[18];
    const float* w_w = (const float*)d_in[19], *b_w = (const float*)d_in[20];
    const float* w3  = (const float*)d_in[21], *b3  = (const float*)d_in[22];
    float* outp = (float*)d_out;

    // workspace layout
    char* ws = (char*)d_ws;
    short* xcl   = (short*)ws;                         // fp16 16.78 MB
    short* h1    = xcl + (size_t)NPX * 64;
    short* h2    = h1 + (size_t)NPX * 64;
    short* wt_om  = h2 + (size_t)NPX * 64;             // 32*576 fp16
    short* wt_dcn = wt_om  + 32 * 576;                 // 64*576 fp16
    short* wt_h   = wt_dcn + 64 * 576;                 // bf16
    short* wt_w   = wt_h   + 64 * 576;                 // bf16
    float* w3t    = (float*)(wt_w + 64 * 576);         // 576 fp32

    dim3 blk(256);
    k_x2cl<<<512, blk, 0, stream>>>(x, xcl, w_om, w_dcn, w_h, w_w, w3,
                                    wt_om, wt_dcn, wt_h, wt_w, w3t);
    k_dcn_mfma<<<NPX / 64, blk, 0, stream>>>(xcl, wt_om, b_om, wt_dcn, b_dcn,
                                             bn1g, bn1b, bn1m, bn1v, h1);
    k_conv_mfma<<<512, dim3(512), 0, stream>>>(h1, wt_h, b_h, bn2g, bn2b, bn2m, bn2v, h2);
    k_conv_mfma<<<512, dim3(512), 0, stream>>>(h2, wt_w, b_w, bn3g, bn3b, bn3m, bn3v, h1);
    k_final<<<512, blk, 0, stream>>>(h1, w3t, b3, outp);
}

// Round 9
// 218.497 us; speedup vs baseline: 1.0682x; 1.0682x over previous
//
#include <hip/hip_runtime.h>
#include <math.h>

#define HH 256
#define WW 256
#define HW (HH*WW)
#define NPX (2*HW)          // 131072 pixels total

typedef __attribute__((ext_vector_type(8))) short bf16x8;
typedef __attribute__((ext_vector_type(8))) _Float16 f16x8;
typedef __attribute__((ext_vector_type(4))) _Float16 f16x4;
typedef __attribute__((ext_vector_type(2))) _Float16 f16x2;
typedef __attribute__((ext_vector_type(4))) float f32x4;

__device__ __forceinline__ float bf2f(short h) {
    union { unsigned u; float f; } v; v.u = ((unsigned)(unsigned short)h) << 16; return v.f;
}
__device__ __forceinline__ short f2bf(float f) {        // RNE
    union { float f; unsigned u; } v; v.f = f;
    unsigned r = v.u + 0x7fffu + ((v.u >> 16) & 1u);
    return (short)(r >> 16);
}
__device__ __forceinline__ short f2hs(float f) {        // f32 -> fp16 bits
    _Float16 h = (_Float16)f;
    union { _Float16 h; short s; } v; v.h = h; return v.s;
}

// ---------- x NCHW fp32 -> channel-last fp16 + weight prep ----------
__global__ __launch_bounds__(256) void k_x2cl(const float* __restrict__ x,
        short* __restrict__ xcl,
        const float* __restrict__ w_om, const float* __restrict__ w_dcn,
        const float* __restrict__ w_h,  const float* __restrict__ w_w,
        const float* __restrict__ w3,
        short* __restrict__ wt_om, short* __restrict__ wt_dcn,
        short* __restrict__ wt_h,  short* __restrict__ wt_w,
        float* __restrict__ w3t) {
    __shared__ short tile[256 * 70];                 // 35,840 B
    const int xx = threadIdx.x;
    const int row = blockIdx.x;               // b*256 + y
    const int b = row >> 8, y = row & 255;
#pragma unroll 8
    for (int c = 0; c < 64; ++c)
        tile[xx * 70 + c] = f2hs(x[((size_t)(b * 64 + c) << 16) + (y << 8) + xx]);
    int i = blockIdx.x * 256 + threadIdx.x;
    if (i < 64 * 576) {
        int o = i / 576, k = i - o * 576, t = k >> 6, c = k & 63;
        int kb = k >> 3, j = k & 7;
        int src = (o * 64 + c) * 9 + t;
        int dst = (kb * 64 + o) * 8 + j;
        wt_dcn[dst] = f2hs(w_dcn[src]);
        wt_h[dst]   = f2bf(w_h[src]);
        wt_w[dst]   = f2bf(w_w[src]);
        if (o < 32) wt_om[(kb * 32 + o) * 8 + j] = (o < 27) ? f2hs(w_om[src]) : (short)0;
        if (o == 0) w3t[k] = w3[c * 9 + t];
    }
    __syncthreads();
    short* op = xcl + ((row << 8) + xx) * 64;
    const int* tp = (const int*)&tile[xx * 70];      // 4B-aligned (140B row stride)
#pragma unroll
    for (int j = 0; j < 8; ++j) {
        int4 v;
        v.x = tp[j * 4 + 0]; v.y = tp[j * 4 + 1];
        v.z = tp[j * 4 + 2]; v.w = tp[j * 4 + 3];
        *(int4*)(op + j * 8) = v;                    // 16B coalesced store
    }
}

#define XPS 72   // LDS pixel stride (shorts): 144B, 16B-aligned

// ---------- FUSED om-conv + modulated deformable conv + BN1 + ReLU ----------
__global__ __launch_bounds__(256) __attribute__((amdgpu_waves_per_eu(2, 4)))
void k_dcn_mfma(const short* __restrict__ xcl,
        const short* __restrict__ wom, const float* __restrict__ b_om,
        const short* __restrict__ wt,
        const float* __restrict__ bias,
        const float* __restrict__ gg, const float* __restrict__ be,
        const float* __restrict__ mu, const float* __restrict__ var,
        short* __restrict__ out_cl) {
    __shared__ short xt[256 * XPS];                 // 36,864 B
    __shared__ _Float16 om_lds[64 * 32];            //  4,096 B
    const int lane = threadIdx.x & 63, wave = threadIdx.x >> 6;
    const int quad = lane >> 4, l16 = lane & 15;
    const int band = blockIdx.x & 7, idx = blockIdx.x >> 3;
    const int tr = band * 8 + (idx >> 5), tc = idx & 31;
    const int b = tr >> 5;
    const int ty0 = (tr & 31) * 8, tx0 = tc * 8;
    const int base = b << 16;
    const int hy0 = ty0 - 4, hx0 = tx0 - 4;
    // ---- stage 16x16 halo (clamped) ----
    {
        const int p = threadIdx.x;
        const int sy = min(max(hy0 + (p >> 4), 0), 255);
        const int sx = min(max(hx0 + (p & 15), 0), 255);
        const short* src = xcl + (size_t)((base + sy * 256 + sx) * 64);
        short* dst = &xt[p * XPS];
#pragma unroll
        for (int j = 0; j < 8; ++j)
            *(bf16x8*)(dst + j * 8) = *(const bf16x8*)(src + j * 8);
    }
    __syncthreads();

    const int lp = wave * 16 + l16;        // tile-local pixel (A-row m=l16)
    const int pyy = lp >> 3, pxx = lp & 7;
    const int y = ty0 + pyy, x = tx0 + pxx;

    // ---- phase 1: om conv for this tile (zero-OOB taps) ----
    {
        f32x4 oacc[2];
        oacc[0] = (f32x4){0,0,0,0}; oacc[1] = (f32x4){0,0,0,0};
        auto loadOB = [&](int s, f16x8* Bv) {
            const int kb = s * 4 + quad;
#pragma unroll
            for (int g = 0; g < 2; ++g)
                Bv[g] = *(const f16x8*)(wom + (kb * 32 + g * 16 + l16) * 8);
        };
        f16x8 OB[2][2];
        loadOB(0, OB[0]);
#pragma unroll
        for (int s = 0; s < 18; ++s) {
            if (s < 17) loadOB(s + 1, OB[(s + 1) & 1]);
            const int t = s >> 1, c0 = (s & 1) * 32;
            const int dy = t / 3 - 1, dx = t % 3 - 1;
            f16x8 av = *(const f16x8*)&xt[((pyy + 4 + dy) * 16 + (pxx + 4 + dx)) * XPS + c0 + quad * 8];
            bool ok = ((unsigned)(y + dy) < 256u) && ((unsigned)(x + dx) < 256u);
            if (!ok) { f16x8 z = {0,0,0,0,0,0,0,0}; av = z; }
#pragma unroll
            for (int g = 0; g < 2; ++g)
                oacc[g] = __builtin_amdgcn_mfma_f32_16x16x32_f16(av, OB[s & 1][g], oacc[g], 0, 0, 0);
        }
#pragma unroll
        for (int g = 0; g < 2; ++g) {
            int o = g * 16 + l16;
            if (o < 27) {
                float bo = b_om[o];
#pragma unroll
                for (int r = 0; r < 4; ++r) {
                    float v = oacc[g][r] + bo;
                    if (o >= 18) v = 1.f / (1.f + expf(-v));     // sigmoid(mask)
                    om_lds[(wave * 16 + quad * 4 + r) * 32 + o] = (_Float16)v;
                }
            }
        }
    }
    __syncthreads();

    // ---- phase 2: deformable conv, branchless, all-LDS gather, B double-buffer ----
    f32x4 acc[4];
#pragma unroll
    for (int i = 0; i < 4; ++i) acc[i] = (f32x4){0,0,0,0};

    _Float16 omh[28];
    *(f16x8*)&omh[0]  = *(const f16x8*)&om_lds[lp * 32];
    *(f16x8*)&omh[8]  = *(const f16x8*)&om_lds[lp * 32 + 8];
    *(f16x8*)&omh[16] = *(const f16x8*)&om_lds[lp * 32 + 16];
    *(f16x4*)&omh[24] = *(const f16x4*)&om_lds[lp * 32 + 24];

    f16x8 BR0[2][4], BR1[2][4];
    auto loadBt = [&](int t, f16x8 B[2][4]) {
#pragma unroll
        for (int h = 0; h < 2; ++h) {
            const int kb = t * 8 + h * 4 + quad;
#pragma unroll
            for (int g = 0; g < 4; ++g)
                B[h][g] = *(const f16x8*)(wt + (kb * 64 + g * 16 + l16) * 8);
        }
    };
    loadBt(0, BR0);

#pragma unroll
    for (int t = 0; t < 9; ++t) {
        f16x8 (*Bc)[4] = (t & 1) ? BR1 : BR0;
        f16x8 (*Bn)[4] = (t & 1) ? BR0 : BR1;
        if (t < 8) loadBt(t + 1, Bn);

        const int ky = t / 3 - 1, kx = t % 3 - 1;
        float o1 = (float)omh[t], o2 = (float)omh[9 + t], m = (float)omh[18 + t];
        float py = (float)(y + ky) + o1;
        float px = (float)(x + kx) + o2;
        float y0f = floorf(py), x0f = floorf(px);
        float wy1 = py - y0f, wx1 = px - x0f;
        int y0 = (int)y0f, xi0 = (int)x0f, y1 = y0 + 1, xi1 = xi0 + 1;
        float w00 = (1.f - wy1) * (1.f - wx1) * m;
        float w01 = (1.f - wy1) * wx1 * m;
        float w10 = wy1 * (1.f - wx1) * m;
        float w11 = wy1 * wx1 * m;
        if (!((unsigned)y0  < 256u)) { w00 = 0.f; w01 = 0.f; }
        if (!((unsigned)y1  < 256u)) { w10 = 0.f; w11 = 0.f; }
        if (!((unsigned)xi0 < 256u)) { w00 = 0.f; w10 = 0.f; }
        if (!((unsigned)xi1 < 256u)) { w01 = 0.f; w11 = 0.f; }
        int cy0 = min(max(y0, 0), 255), cy1 = min(max(y1, 0), 255);
        int cx0 = min(max(xi0, 0), 255), cx1 = min(max(xi1, 0), 255);
        int iy0 = cy0 - hy0, iy1 = cy1 - hy0;
        int ix0 = cx0 - hx0, ix1 = cx1 - hx0;
        if (!((unsigned)iy0 < 16u)) { w00 = 0.f; w01 = 0.f; iy0 = min(max(iy0, 0), 15); }
        if (!((unsigned)iy1 < 16u)) { w10 = 0.f; w11 = 0.f; iy1 = min(max(iy1, 0), 15); }
        if (!((unsigned)ix0 < 16u)) { w00 = 0.f; w10 = 0.f; ix0 = min(max(ix0, 0), 15); }
        if (!((unsigned)ix1 < 16u)) { w01 = 0.f; w11 = 0.f; ix1 = min(max(ix1, 0), 15); }

        const int p00 = (iy0 * 16 + ix0) * XPS, p01 = (iy0 * 16 + ix1) * XPS;
        const int p10 = (iy1 * 16 + ix0) * XPS, p11 = (iy1 * 16 + ix1) * XPS;
        f16x8 C[2][4];
#pragma unroll
        for (int h = 0; h < 2; ++h) {
            const int cb = h * 32 + quad * 8;
            C[h][0] = *(const f16x8*)&xt[p00 + cb];
            C[h][1] = *(const f16x8*)&xt[p01 + cb];
            C[h][2] = *(const f16x8*)&xt[p10 + cb];
            C[h][3] = *(const f16x8*)&xt[p11 + cb];
        }
        const _Float16 h00 = (_Float16)w00, h01 = (_Float16)w01;
        const _Float16 h10 = (_Float16)w10, h11 = (_Float16)w11;
        const f16x2 W00 = {h00, h00}, W01 = {h01, h01};
        const f16x2 W10 = {h10, h10}, W11 = {h11, h11};
#pragma unroll
        for (int h = 0; h < 2; ++h) {
            const f16x2* c0 = (const f16x2*)&C[h][0];
            const f16x2* c1 = (const f16x2*)&C[h][1];
            const f16x2* c2 = (const f16x2*)&C[h][2];
            const f16x2* c3 = (const f16x2*)&C[h][3];
            f16x8 av;
            f16x2* avp = (f16x2*)&av;
#pragma unroll
            for (int d = 0; d < 4; ++d) {
                f16x2 s = c0[d] * W00;
                s = __builtin_elementwise_fma(c1[d], W01, s);
                s = __builtin_elementwise_fma(c2[d], W10, s);
                s = __builtin_elementwise_fma(c3[d], W11, s);
                avp[d] = s;
            }
#pragma unroll
            for (int g = 0; g < 4; ++g)
                acc[g] = __builtin_amdgcn_mfma_f32_16x16x32_f16(av, Bc[h][g], acc[g], 0, 0, 0);
        }
    }
#pragma unroll
    for (int g = 0; g < 4; ++g) {
        int o = g * 16 + l16;
        float sc = gg[o] * rsqrtf(var[o] + 1e-5f);
        float off = (bias[o] - mu[o]) * sc + be[o];
#pragma unroll
        for (int r = 0; r < 4; ++r) {
            int mm = quad * 4 + r;
            int pix = base + ((ty0 + wave * 2 + (mm >> 3)) << 8) + tx0 + (mm & 7);
            float v = acc[g][r] * sc + off;
            out_cl[(size_t)pix * 64 + o] = f2bf(fmaxf(v, 0.f));
        }
    }
}

// ---------- dilated conv (dil=2 pad=2): 8x8 tile + 12x12 halo, 256 thr, 2048 blocks ----------
// LDS 20.7KB -> up to 7 blocks/CU (grid gives 8) => ~24-28 waves/CU vs 16 before.
__global__ __launch_bounds__(256)
void k_conv_mfma(const short* __restrict__ in_cl,
        const short* __restrict__ wt, const float* __restrict__ bias,
        const float* __restrict__ gg, const float* __restrict__ be,
        const float* __restrict__ mu, const float* __restrict__ var,
        short* __restrict__ out_cl) {
    __shared__ short xt[144 * XPS];                  // 20,736 B
    const int lane = threadIdx.x & 63, wave = threadIdx.x >> 6;
    const int quad = lane >> 4, l16 = lane & 15;
    const int band = blockIdx.x & 7, idx = blockIdx.x >> 3;      // 2048 blocks
    const int tr = band * 8 + (idx >> 5), tc = idx & 31;
    const int b = tr >> 5;
    const int ty0 = (tr & 31) * 8, tx0 = tc * 8;
    const int base = b << 16;
    // ---- stage 12x12 halo (zero-fill OOB), chunk-strided ----
    for (int i = threadIdx.x; i < 144 * 8; i += 256) {
        const int p = i >> 3, j = i & 7;
        const int sy = ty0 - 2 + p / 12, sx = tx0 - 2 + p % 12;
        bf16x8 v = {0,0,0,0,0,0,0,0};
        if (((unsigned)sy < 256u) && ((unsigned)sx < 256u))
            v = *(const bf16x8*)(in_cl + (size_t)((base + sy * 256 + sx) * 64 + j * 8));
        *(bf16x8*)(&xt[p * XPS + j * 8]) = v;
    }
    __syncthreads();

    const int lp = wave * 16 + l16;          // this wave's 16 output pixels
    const int pyy = lp >> 3, pxx = lp & 7;

    f32x4 acc[4];
#pragma unroll
    for (int g = 0; g < 4; ++g) acc[g] = (f32x4){0,0,0,0};

    auto loadB = [&](int s, bf16x8* Bv) {
        const int kb = s * 4 + quad;
#pragma unroll
        for (int g = 0; g < 4; ++g)
            Bv[g] = *(const bf16x8*)(wt + (kb * 64 + g * 16 + l16) * 8);
    };
    bf16x8 B[3][4];
    loadB(0, B[0]);
    loadB(1, B[1]);
#pragma unroll
    for (int s = 0; s < 18; ++s) {
        if (s + 2 < 18) loadB(s + 2, B[(s + 2) % 3]);
        const int t = s >> 1, c0 = (s & 1) * 32;
        const int dy = (t / 3 - 1) * 2, dx = (t % 3 - 1) * 2;
        bf16x8 av = *(const bf16x8*)&xt[((pyy + 2 + dy) * 12 + (pxx + 2 + dx)) * XPS + c0 + quad * 8];
#pragma unroll
        for (int g = 0; g < 4; ++g)
            acc[g] = __builtin_amdgcn_mfma_f32_16x16x32_bf16(av, B[s % 3][g], acc[g], 0, 0, 0);
    }
#pragma unroll
    for (int g = 0; g < 4; ++g) {
        int o = g * 16 + l16;
        float sc = gg[o] * rsqrtf(var[o] + 1e-5f);
        float off = (bias[o] - mu[o]) * sc + be[o];
#pragma unroll
        for (int r = 0; r < 4; ++r) {
            int mm = quad * 4 + r;
            int pix = base + ((ty0 + wave * 2 + (mm >> 3)) << 8) + tx0 + (mm & 7);
            float v = acc[g][r] * sc + off;
            out_cl[(size_t)pix * 64 + o] = f2bf(fmaxf(v, 0.f));
        }
    }
}

// ---------- final 3x3 conv (pad=1) + sigmoid + clip : 16x16 tile + 18x18 halo ----------
__global__ __launch_bounds__(256) void k_final(const short* __restrict__ h_cl,
        const float* __restrict__ w3t, const float* __restrict__ b3,
        float* __restrict__ out) {
    __shared__ short xt[324 * XPS];                  // 46.7 KB
    const int tIdx = (blockIdx.x & 7) * 64 + (blockIdx.x >> 3);   // 512 blocks
    const int tr = tIdx >> 4, tc = tIdx & 15;
    const int b = tr >> 4;
    const int ty0 = (tr & 15) * 16, tx0 = tc * 16;
    const int base = b << 16;
    for (int i = threadIdx.x; i < 324 * 8; i += 256) {
        const int p = i >> 3, j = i & 7;
        const int sy = ty0 - 1 + p / 18, sx = tx0 - 1 + p % 18;
        bf16x8 v = {0,0,0,0,0,0,0,0};
        if (((unsigned)sy < 256u) && ((unsigned)sx < 256u))
            v = *(const bf16x8*)(h_cl + (size_t)((base + sy * 256 + sx) * 64 + j * 8));
        *(bf16x8*)(&xt[p * XPS + j * 8]) = v;
    }
    __syncthreads();
    const int ly = threadIdx.x >> 4, lx = threadIdx.x & 15;
    float a0 = 0.f, a1 = 0.f, a2 = 0.f, a3 = 0.f;
#pragma unroll
    for (int t = 0; t < 9; ++t) {
        const int hidx = (ly + 1 + t / 3 - 1) * 18 + (lx + 1 + t % 3 - 1);
        const short* hp = &xt[hidx * XPS];
        const float* wp = w3t + t * 64;
#pragma unroll
        for (int j = 0; j < 64; j += 32) {
            bf16x8 v0 = *(const bf16x8*)(hp + j);
            bf16x8 v1 = *(const bf16x8*)(hp + j + 8);
            bf16x8 v2 = *(const bf16x8*)(hp + j + 16);
            bf16x8 v3 = *(const bf16x8*)(hp + j + 24);
#pragma unroll
            for (int e = 0; e < 8; ++e) {
                a0 = fmaf(bf2f(v0[e]), wp[j + e], a0);
                a1 = fmaf(bf2f(v1[e]), wp[j + 8 + e], a1);
                a2 = fmaf(bf2f(v2[e]), wp[j + 16 + e], a2);
                a3 = fmaf(bf2f(v3[e]), wp[j + 24 + e], a3);
            }
        }
    }
    float acc = (a0 + a1) + (a2 + a3);
    float s = 1.f / (1.f + expf(-(acc + b3[0])));
    out[base + ((ty0 + ly) << 8) + tx0 + lx] = fminf(fmaxf(s, 1e-4f), 1.f - 1e-4f);
}

extern "C" void kernel_launch(void* const* d_in, const int* in_sizes, int n_in,
                              void* d_out, int out_size, void* d_ws, size_t ws_size,
                              hipStream_t stream) {
    const float* x     = (const float*)d_in[0];
    const float* w_om  = (const float*)d_in[1];
    const float* b_om  = (const float*)d_in[2];
    const float* w_dcn = (const float*)d_in[3];
    const float* b_dcn = (const float*)d_in[4];
    const float* bn1g = (const float*)d_in[5],  *bn1b = (const float*)d_in[6];
    const float* bn1m = (const float*)d_in[7],  *bn1v = (const float*)d_in[8];
    const float* bn2g = (const float*)d_in[9],  *bn2b = (const float*)d_in[10];
    const float* bn2m = (const float*)d_in[11], *bn2v = (const float*)d_in[12];
    const float* bn3g = (const float*)d_in[13], *bn3b = (const float*)d_in[14];
    const float* bn3m = (const float*)d_in[15], *bn3v = (const float*)d_in[16];
    const float* w_h = (const float*)d_in[17], *b_h = (const float*)d_in[18];
    const float* w_w = (const float*)d_in[19], *b_w = (const float*)d_in[20];
    const float* w3  = (const float*)d_in[21], *b3  = (const float*)d_in[22];
    float* outp = (float*)d_out;

    // workspace layout
    char* ws = (char*)d_ws;
    short* xcl   = (short*)ws;                         // fp16 16.78 MB
    short* h1    = xcl + (size_t)NPX * 64;
    short* h2    = h1 + (size_t)NPX * 64;
    short* wt_om  = h2 + (size_t)NPX * 64;             // 32*576 fp16
    short* wt_dcn = wt_om  + 32 * 576;                 // 64*576 fp16
    short* wt_h   = wt_dcn + 64 * 576;                 // bf16
    short* wt_w   = wt_h   + 64 * 576;                 // bf16
    float* w3t    = (float*)(wt_w + 64 * 576);         // 576 fp32

    dim3 blk(256);
    k_x2cl<<<512, blk, 0, stream>>>(x, xcl, w_om, w_dcn, w_h, w_w, w3,
                                    wt_om, wt_dcn, wt_h, wt_w, w3t);
    k_dcn_mfma<<<NPX / 64, blk, 0, stream>>>(xcl, wt_om, b_om, wt_dcn, b_dcn,
                                             bn1g, bn1b, bn1m, bn1v, h1);
    k_conv_mfma<<<2048, blk, 0, stream>>>(h1, wt_h, b_h, bn2g, bn2b, bn2m, bn2v, h2);
    k_conv_mfma<<<2048, blk, 0, stream>>>(h2, wt_w, b_w, bn3g, bn3b, bn3m, bn3v, h1);
    k_final<<<512, blk, 0, stream>>>(h1, w3t, b3, outp);
}

// Round 10
// 212.921 us; speedup vs baseline: 1.0961x; 1.0262x over previous
//
#include <hip/hip_runtime.h>
#include <math.h>

#define HH 256
#define WW 256
#define HW (HH*WW)
#define NPX (2*HW)          // 131072 pixels total

typedef __attribute__((ext_vector_type(8))) short bf16x8;
typedef __attribute__((ext_vector_type(8))) _Float16 f16x8;
typedef __attribute__((ext_vector_type(4))) _Float16 f16x4;
typedef __attribute__((ext_vector_type(2))) _Float16 f16x2;
typedef __attribute__((ext_vector_type(4))) float f32x4;

__device__ __forceinline__ float bf2f(short h) {
    union { unsigned u; float f; } v; v.u = ((unsigned)(unsigned short)h) << 16; return v.f;
}
__device__ __forceinline__ short f2bf(float f) {        // RNE
    union { float f; unsigned u; } v; v.f = f;
    unsigned r = v.u + 0x7fffu + ((v.u >> 16) & 1u);
    return (short)(r >> 16);
}
__device__ __forceinline__ short f2hs(float f) {        // f32 -> fp16 bits
    _Float16 h = (_Float16)f;
    union { _Float16 h; short s; } v; v.h = h; return v.s;
}

// ---------- x NCHW fp32 -> channel-last fp16 + weight prep ----------
__global__ __launch_bounds__(256) void k_x2cl(const float* __restrict__ x,
        short* __restrict__ xcl,
        const float* __restrict__ w_om, const float* __restrict__ w_dcn,
        const float* __restrict__ w_h,  const float* __restrict__ w_w,
        const float* __restrict__ w3,
        short* __restrict__ wt_om, short* __restrict__ wt_dcn,
        short* __restrict__ wt_h,  short* __restrict__ wt_w,
        float* __restrict__ w3t) {
    __shared__ short tile[256 * 70];                 // 35,840 B
    const int xx = threadIdx.x;
    const int row = blockIdx.x;               // b*256 + y
    const int b = row >> 8, y = row & 255;
#pragma unroll 8
    for (int c = 0; c < 64; ++c)
        tile[xx * 70 + c] = f2hs(x[((size_t)(b * 64 + c) << 16) + (y << 8) + xx]);
    int i = blockIdx.x * 256 + threadIdx.x;
    if (i < 64 * 576) {
        int o = i / 576, k = i - o * 576, t = k >> 6, c = k & 63;
        int kb = k >> 3, j = k & 7;
        int src = (o * 64 + c) * 9 + t;
        int dst = (kb * 64 + o) * 8 + j;
        wt_dcn[dst] = f2hs(w_dcn[src]);
        wt_h[dst]   = f2bf(w_h[src]);
        wt_w[dst]   = f2bf(w_w[src]);
        if (o < 32) wt_om[(kb * 32 + o) * 8 + j] = (o < 27) ? f2hs(w_om[src]) : (short)0;
        if (o == 0) w3t[k] = w3[c * 9 + t];
    }
    __syncthreads();
    short* op = xcl + ((row << 8) + xx) * 64;
    const int* tp = (const int*)&tile[xx * 70];      // 4B-aligned (140B row stride)
#pragma unroll
    for (int j = 0; j < 8; ++j) {
        int4 v;
        v.x = tp[j * 4 + 0]; v.y = tp[j * 4 + 1];
        v.z = tp[j * 4 + 2]; v.w = tp[j * 4 + 3];
        *(int4*)(op + j * 8) = v;                    // 16B coalesced store
    }
}

#define XPS 72   // LDS pixel stride (shorts): 144B, 16B-aligned

// ---------- FUSED om-conv + modulated deformable conv + BN1 + ReLU ----------
__global__ __launch_bounds__(256) __attribute__((amdgpu_waves_per_eu(2, 4)))
void k_dcn_mfma(const short* __restrict__ xcl,
        const short* __restrict__ wom, const float* __restrict__ b_om,
        const short* __restrict__ wt,
        const float* __restrict__ bias,
        const float* __restrict__ gg, const float* __restrict__ be,
        const float* __restrict__ mu, const float* __restrict__ var,
        short* __restrict__ out_cl) {
    __shared__ short xt[256 * XPS];                 // 36,864 B
    __shared__ _Float16 om_lds[64 * 32];            //  4,096 B
    const int lane = threadIdx.x & 63, wave = threadIdx.x >> 6;
    const int quad = lane >> 4, l16 = lane & 15;
    const int band = blockIdx.x & 7, idx = blockIdx.x >> 3;
    const int tr = band * 8 + (idx >> 5), tc = idx & 31;
    const int b = tr >> 5;
    const int ty0 = (tr & 31) * 8, tx0 = tc * 8;
    const int base = b << 16;
    const int hy0 = ty0 - 4, hx0 = tx0 - 4;
    // ---- stage 16x16 halo (clamped) ----
    {
        const int p = threadIdx.x;
        const int sy = min(max(hy0 + (p >> 4), 0), 255);
        const int sx = min(max(hx0 + (p & 15), 0), 255);
        const short* src = xcl + (size_t)((base + sy * 256 + sx) * 64);
        short* dst = &xt[p * XPS];
#pragma unroll
        for (int j = 0; j < 8; ++j)
            *(bf16x8*)(dst + j * 8) = *(const bf16x8*)(src + j * 8);
    }
    __syncthreads();

    const int lp = wave * 16 + l16;        // tile-local pixel (A-row m=l16)
    const int pyy = lp >> 3, pxx = lp & 7;
    const int y = ty0 + pyy, x = tx0 + pxx;

    // ---- phase 1: om conv for this tile (zero-OOB taps) ----
    {
        f32x4 oacc[2];
        oacc[0] = (f32x4){0,0,0,0}; oacc[1] = (f32x4){0,0,0,0};
        auto loadOB = [&](int s, f16x8* Bv) {
            const int kb = s * 4 + quad;
#pragma unroll
            for (int g = 0; g < 2; ++g)
                Bv[g] = *(const f16x8*)(wom + (kb * 32 + g * 16 + l16) * 8);
        };
        f16x8 OB[2][2];
        loadOB(0, OB[0]);
#pragma unroll
        for (int s = 0; s < 18; ++s) {
            if (s < 17) loadOB(s + 1, OB[(s + 1) & 1]);
            const int t = s >> 1, c0 = (s & 1) * 32;
            const int dy = t / 3 - 1, dx = t % 3 - 1;
            f16x8 av = *(const f16x8*)&xt[((pyy + 4 + dy) * 16 + (pxx + 4 + dx)) * XPS + c0 + quad * 8];
            bool ok = ((unsigned)(y + dy) < 256u) && ((unsigned)(x + dx) < 256u);
            if (!ok) { f16x8 z = {0,0,0,0,0,0,0,0}; av = z; }
#pragma unroll
            for (int g = 0; g < 2; ++g)
                oacc[g] = __builtin_amdgcn_mfma_f32_16x16x32_f16(av, OB[s & 1][g], oacc[g], 0, 0, 0);
        }
#pragma unroll
        for (int g = 0; g < 2; ++g) {
            int o = g * 16 + l16;
            if (o < 27) {
                float bo = b_om[o];
#pragma unroll
                for (int r = 0; r < 4; ++r) {
                    float v = oacc[g][r] + bo;
                    if (o >= 18) v = 1.f / (1.f + expf(-v));     // sigmoid(mask)
                    om_lds[(wave * 16 + quad * 4 + r) * 32 + o] = (_Float16)v;
                }
            }
        }
    }
    __syncthreads();

    // ---- phase 2: deformable conv, branchless, all-LDS gather, B double-buffer ----
    f32x4 acc[4];
#pragma unroll
    for (int i = 0; i < 4; ++i) acc[i] = (f32x4){0,0,0,0};

    _Float16 omh[28];
    *(f16x8*)&omh[0]  = *(const f16x8*)&om_lds[lp * 32];
    *(f16x8*)&omh[8]  = *(const f16x8*)&om_lds[lp * 32 + 8];
    *(f16x8*)&omh[16] = *(const f16x8*)&om_lds[lp * 32 + 16];
    *(f16x4*)&omh[24] = *(const f16x4*)&om_lds[lp * 32 + 24];

    f16x8 BR0[2][4], BR1[2][4];
    auto loadBt = [&](int t, f16x8 B[2][4]) {
#pragma unroll
        for (int h = 0; h < 2; ++h) {
            const int kb = t * 8 + h * 4 + quad;
#pragma unroll
            for (int g = 0; g < 4; ++g)
                B[h][g] = *(const f16x8*)(wt + (kb * 64 + g * 16 + l16) * 8);
        }
    };
    loadBt(0, BR0);

#pragma unroll
    for (int t = 0; t < 9; ++t) {
        f16x8 (*Bc)[4] = (t & 1) ? BR1 : BR0;
        f16x8 (*Bn)[4] = (t & 1) ? BR0 : BR1;
        if (t < 8) loadBt(t + 1, Bn);

        const int ky = t / 3 - 1, kx = t % 3 - 1;
        float o1 = (float)omh[t], o2 = (float)omh[9 + t], m = (float)omh[18 + t];
        float py = (float)(y + ky) + o1;
        float px = (float)(x + kx) + o2;
        float y0f = floorf(py), x0f = floorf(px);
        float wy1 = py - y0f, wx1 = px - x0f;
        int y0 = (int)y0f, xi0 = (int)x0f, y1 = y0 + 1, xi1 = xi0 + 1;
        float w00 = (1.f - wy1) * (1.f - wx1) * m;
        float w01 = (1.f - wy1) * wx1 * m;
        float w10 = wy1 * (1.f - wx1) * m;
        float w11 = wy1 * wx1 * m;
        if (!((unsigned)y0  < 256u)) { w00 = 0.f; w01 = 0.f; }
        if (!((unsigned)y1  < 256u)) { w10 = 0.f; w11 = 0.f; }
        if (!((unsigned)xi0 < 256u)) { w00 = 0.f; w10 = 0.f; }
        if (!((unsigned)xi1 < 256u)) { w01 = 0.f; w11 = 0.f; }
        int cy0 = min(max(y0, 0), 255), cy1 = min(max(y1, 0), 255);
        int cx0 = min(max(xi0, 0), 255), cx1 = min(max(xi1, 0), 255);
        int iy0 = cy0 - hy0, iy1 = cy1 - hy0;
        int ix0 = cx0 - hx0, ix1 = cx1 - hx0;
        if (!((unsigned)iy0 < 16u)) { w00 = 0.f; w01 = 0.f; iy0 = min(max(iy0, 0), 15); }
        if (!((unsigned)iy1 < 16u)) { w10 = 0.f; w11 = 0.f; iy1 = min(max(iy1, 0), 15); }
        if (!((unsigned)ix0 < 16u)) { w00 = 0.f; w10 = 0.f; ix0 = min(max(ix0, 0), 15); }
        if (!((unsigned)ix1 < 16u)) { w01 = 0.f; w11 = 0.f; ix1 = min(max(ix1, 0), 15); }

        const int p00 = (iy0 * 16 + ix0) * XPS, p01 = (iy0 * 16 + ix1) * XPS;
        const int p10 = (iy1 * 16 + ix0) * XPS, p11 = (iy1 * 16 + ix1) * XPS;
        f16x8 C[2][4];
#pragma unroll
        for (int h = 0; h < 2; ++h) {
            const int cb = h * 32 + quad * 8;
            C[h][0] = *(const f16x8*)&xt[p00 + cb];
            C[h][1] = *(const f16x8*)&xt[p01 + cb];
            C[h][2] = *(const f16x8*)&xt[p10 + cb];
            C[h][3] = *(const f16x8*)&xt[p11 + cb];
        }
        const _Float16 h00 = (_Float16)w00, h01 = (_Float16)w01;
        const _Float16 h10 = (_Float16)w10, h11 = (_Float16)w11;
        const f16x2 W00 = {h00, h00}, W01 = {h01, h01};
        const f16x2 W10 = {h10, h10}, W11 = {h11, h11};
#pragma unroll
        for (int h = 0; h < 2; ++h) {
            const f16x2* c0 = (const f16x2*)&C[h][0];
            const f16x2* c1 = (const f16x2*)&C[h][1];
            const f16x2* c2 = (const f16x2*)&C[h][2];
            const f16x2* c3 = (const f16x2*)&C[h][3];
            f16x8 av;
            f16x2* avp = (f16x2*)&av;
#pragma unroll
            for (int d = 0; d < 4; ++d) {
                f16x2 s = c0[d] * W00;
                s = __builtin_elementwise_fma(c1[d], W01, s);
                s = __builtin_elementwise_fma(c2[d], W10, s);
                s = __builtin_elementwise_fma(c3[d], W11, s);
                avp[d] = s;
            }
            __builtin_amdgcn_s_setprio(1);
#pragma unroll
            for (int g = 0; g < 4; ++g)
                acc[g] = __builtin_amdgcn_mfma_f32_16x16x32_f16(av, Bc[h][g], acc[g], 0, 0, 0);
            __builtin_amdgcn_s_setprio(0);
        }
    }
#pragma unroll
    for (int g = 0; g < 4; ++g) {
        int o = g * 16 + l16;
        float sc = gg[o] * rsqrtf(var[o] + 1e-5f);
        float off = (bias[o] - mu[o]) * sc + be[o];
#pragma unroll
        for (int r = 0; r < 4; ++r) {
            int mm = quad * 4 + r;
            int pix = base + ((ty0 + wave * 2 + (mm >> 3)) << 8) + tx0 + (mm & 7);
            float v = acc[g][r] * sc + off;
            out_cl[(size_t)pix * 64 + o] = f2bf(fmaxf(v, 0.f));
        }
    }
}

// ---------- dilated conv (dil=2 pad=2): 16x16 tile + 20x20 halo, 512 thr (r6 form) ----------
__global__ __launch_bounds__(512) __attribute__((amdgpu_waves_per_eu(2, 4)))
void k_conv_mfma(const short* __restrict__ in_cl,
        const short* __restrict__ wt, const float* __restrict__ bias,
        const float* __restrict__ gg, const float* __restrict__ be,
        const float* __restrict__ mu, const float* __restrict__ var,
        short* __restrict__ out_cl) {
    __shared__ short xt[400 * XPS];                  // 57.6 KB
    const int lane = threadIdx.x & 63, wave = threadIdx.x >> 6;   // wave 0..7
    const int quad = lane >> 4, l16 = lane & 15;
    const int tIdx = (blockIdx.x & 7) * 64 + (blockIdx.x >> 3);   // 512 blocks
    const int tr = tIdx >> 4, tc = tIdx & 15;
    const int b = tr >> 4;
    const int ty0 = (tr & 15) * 16, tx0 = tc * 16;
    const int base = b << 16;
    for (int i = threadIdx.x; i < 400 * 8; i += 512) {
        const int p = i >> 3, j = i & 7;
        const int sy = ty0 - 2 + p / 20, sx = tx0 - 2 + p % 20;
        bf16x8 v = {0,0,0,0,0,0,0,0};
        if (((unsigned)sy < 256u) && ((unsigned)sx < 256u))
            v = *(const bf16x8*)(in_cl + (size_t)((base + sy * 256 + sx) * 64 + j * 8));
        *(bf16x8*)(&xt[p * XPS + j * 8]) = v;
    }
    __syncthreads();
    const int ly = wave * 2;                 // rows ly, ly+1
    f32x4 acc[2][4];
#pragma unroll
    for (int h = 0; h < 2; ++h)
#pragma unroll
        for (int g = 0; g < 4; ++g) acc[h][g] = (f32x4){0,0,0,0};

    auto loadB = [&](int s, bf16x8* Bv) {
        const int kb = s * 4 + quad;
#pragma unroll
        for (int g = 0; g < 4; ++g)
            Bv[g] = *(const bf16x8*)(wt + (kb * 64 + g * 16 + l16) * 8);
    };
    bf16x8 B[3][4];
    loadB(0, B[0]);
    loadB(1, B[1]);
#pragma unroll
    for (int s = 0; s < 18; ++s) {
        if (s + 2 < 18) loadB(s + 2, B[(s + 2) % 3]);
        const int t = s >> 1, c0 = (s & 1) * 32;
        const int dy = (t / 3 - 1) * 2, dx = (t % 3 - 1) * 2;
        const int cidx = c0 + quad * 8;
        bf16x8 a0 = *(const bf16x8*)&xt[((ly + 2 + dy) * 20 + (l16 + 2 + dx)) * XPS + cidx];
        bf16x8 a1 = *(const bf16x8*)&xt[((ly + 3 + dy) * 20 + (l16 + 2 + dx)) * XPS + cidx];
        __builtin_amdgcn_s_setprio(1);
#pragma unroll
        for (int g = 0; g < 4; ++g) {
            acc[0][g] = __builtin_amdgcn_mfma_f32_16x16x32_bf16(a0, B[s % 3][g], acc[0][g], 0, 0, 0);
            acc[1][g] = __builtin_amdgcn_mfma_f32_16x16x32_bf16(a1, B[s % 3][g], acc[1][g], 0, 0, 0);
        }
        __builtin_amdgcn_s_setprio(0);
    }
#pragma unroll
    for (int h = 0; h < 2; ++h)
#pragma unroll
    for (int g = 0; g < 4; ++g) {
        int o = g * 16 + l16;
        float sc = gg[o] * rsqrtf(var[o] + 1e-5f);
        float off = (bias[o] - mu[o]) * sc + be[o];
#pragma unroll
        for (int r = 0; r < 4; ++r) {
            int pix = base + ((ty0 + ly + h) << 8) + tx0 + quad * 4 + r;
            float v = acc[h][g][r] * sc + off;
            out_cl[(size_t)pix * 64 + o] = f2bf(fmaxf(v, 0.f));
        }
    }
}

// ---------- final 3x3 conv (pad=1) + sigmoid + clip : 16x16 tile + 18x18 halo ----------
__global__ __launch_bounds__(256) void k_final(const short* __restrict__ h_cl,
        const float* __restrict__ w3t, const float* __restrict__ b3,
        float* __restrict__ out) {
    __shared__ short xt[324 * XPS];                  // 46.7 KB
    const int tIdx = (blockIdx.x & 7) * 64 + (blockIdx.x >> 3);   // 512 blocks
    const int tr = tIdx >> 4, tc = tIdx & 15;
    const int b = tr >> 4;
    const int ty0 = (tr & 15) * 16, tx0 = tc * 16;
    const int base = b << 16;
    for (int i = threadIdx.x; i < 324 * 8; i += 256) {
        const int p = i >> 3, j = i & 7;
        const int sy = ty0 - 1 + p / 18, sx = tx0 - 1 + p % 18;
        bf16x8 v = {0,0,0,0,0,0,0,0};
        if (((unsigned)sy < 256u) && ((unsigned)sx < 256u))
            v = *(const bf16x8*)(h_cl + (size_t)((base + sy * 256 + sx) * 64 + j * 8));
        *(bf16x8*)(&xt[p * XPS + j * 8]) = v;
    }
    __syncthreads();
    const int ly = threadIdx.x >> 4, lx = threadIdx.x & 15;
    float a0 = 0.f, a1 = 0.f, a2 = 0.f, a3 = 0.f;
#pragma unroll
    for (int t = 0; t < 9; ++t) {
        const int hidx = (ly + 1 + t / 3 - 1) * 18 + (lx + 1 + t % 3 - 1);
        const short* hp = &xt[hidx * XPS];
        const float* wp = w3t + t * 64;
#pragma unroll
        for (int j = 0; j < 64; j += 32) {
            bf16x8 v0 = *(const bf16x8*)(hp + j);
            bf16x8 v1 = *(const bf16x8*)(hp + j + 8);
            bf16x8 v2 = *(const bf16x8*)(hp + j + 16);
            bf16x8 v3 = *(const bf16x8*)(hp + j + 24);
#pragma unroll
            for (int e = 0; e < 8; ++e) {
                a0 = fmaf(bf2f(v0[e]), wp[j + e], a0);
                a1 = fmaf(bf2f(v1[e]), wp[j + 8 + e], a1);
                a2 = fmaf(bf2f(v2[e]), wp[j + 16 + e], a2);
                a3 = fmaf(bf2f(v3[e]), wp[j + 24 + e], a3);
            }
        }
    }
    float acc = (a0 + a1) + (a2 + a3);
    float s = 1.f / (1.f + expf(-(acc + b3[0])));
    out[base + ((ty0 + ly) << 8) + tx0 + lx] = fminf(fmaxf(s, 1e-4f), 1.f - 1e-4f);
}

extern "C" void kernel_launch(void* const* d_in, const int* in_sizes, int n_in,
                              void* d_out, int out_size, void* d_ws, size_t ws_size,
                              hipStream_t stream) {
    const float* x     = (const float*)d_in[0];
    const float* w_om  = (const float*)d_in[1];
    const float* b_om  = (const float*)d_in[2];
    const float* w_dcn = (const float*)d_in[3];
    const float* b_dcn = (const float*)d_in[4];
    const float* bn1g = (const float*)d_in[5],  *bn1b = (const float*)d_in[6];
    const float* bn1m = (const float*)d_in[7],  *bn1v = (const float*)d_in[8];
    const float* bn2g = (const float*)d_in[9],  *bn2b = (const float*)d_in[10];
    const float* bn2m = (const float*)d_in[11], *bn2v = (const float*)d_in[12];
    const float* bn3g = (const float*)d_in[13], *bn3b = (const float*)d_in[14];
    const float* bn3m = (const float*)d_in[15], *bn3v = (const float*)d_in[16];
    const float* w_h = (const float*)d_in[17], *b_h = (const float*)d_in[18];
    const float* w_w = (const float*)d_in[19], *b_w = (const float*)d_in[20];
    const float* w3  = (const float*)d_in[21], *b3  = (const float*)d_in[22];
    float* outp = (float*)d_out;

    // workspace layout
    char* ws = (char*)d_ws;
    short* xcl   = (short*)ws;                         // fp16 16.78 MB
    short* h1    = xcl + (size_t)NPX * 64;
    short* h2    = h1 + (size_t)NPX * 64;
    short* wt_om  = h2 + (size_t)NPX * 64;             // 32*576 fp16
    short* wt_dcn = wt_om  + 32 * 576;                 // 64*576 fp16
    short* wt_h   = wt_dcn + 64 * 576;                 // bf16
    short* wt_w   = wt_h   + 64 * 576;                 // bf16
    float* w3t    = (float*)(wt_w + 64 * 576);         // 576 fp32

    dim3 blk(256);
    k_x2cl<<<512, blk, 0, stream>>>(x, xcl, w_om, w_dcn, w_h, w_w, w3,
                                    wt_om, wt_dcn, wt_h, wt_w, w3t);
    k_dcn_mfma<<<NPX / 64, blk, 0, stream>>>(xcl, wt_om, b_om, wt_dcn, b_dcn,
                                             bn1g, bn1b, bn1m, bn1v, h1);
    k_conv_mfma<<<512, dim3(512), 0, stream>>>(h1, wt_h, b_h, bn2g, bn2b, bn2m, bn2v, h2);
    k_conv_mfma<<<512, dim3(512), 0, stream>>>(h2, wt_w, b_w, bn3g, bn3b, bn3m, bn3v, h1);
    k_final<<<512, blk, 0, stream>>>(h1, w3t, b3, outp);
}

// Round 11
// 206.664 us; speedup vs baseline: 1.1293x; 1.0303x over previous
//
#include <hip/hip_runtime.h>
#include <math.h>

#define HH 256
#define WW 256
#define HW (HH*WW)
#define NPX (2*HW)          // 131072 pixels total

typedef __attribute__((ext_vector_type(8))) short bf16x8;
typedef __attribute__((ext_vector_type(8))) _Float16 f16x8;
typedef __attribute__((ext_vector_type(4))) _Float16 f16x4;
typedef __attribute__((ext_vector_type(2))) _Float16 f16x2;
typedef __attribute__((ext_vector_type(4))) float f32x4;

__device__ __forceinline__ float bf2f(short h) {
    union { unsigned u; float f; } v; v.u = ((unsigned)(unsigned short)h) << 16; return v.f;
}
__device__ __forceinline__ short f2bf(float f) {        // RNE
    union { float f; unsigned u; } v; v.f = f;
    unsigned r = v.u + 0x7fffu + ((v.u >> 16) & 1u);
    return (short)(r >> 16);
}
__device__ __forceinline__ short f2hs(float f) {        // f32 -> fp16 bits
    _Float16 h = (_Float16)f;
    union { _Float16 h; short s; } v; v.h = h; return v.s;
}

// ---------- x NCHW fp32 -> channel-last fp16 + weight prep ----------
__global__ __launch_bounds__(256) void k_x2cl(const float* __restrict__ x,
        short* __restrict__ xcl,
        const float* __restrict__ w_om, const float* __restrict__ w_dcn,
        const float* __restrict__ w_h,  const float* __restrict__ w_w,
        const float* __restrict__ w3,
        short* __restrict__ wt_om, short* __restrict__ wt_dcn,
        short* __restrict__ wt_h,  short* __restrict__ wt_w,
        float* __restrict__ w3t) {
    __shared__ short tile[256 * 70];                 // 35,840 B
    const int xx = threadIdx.x;
    const int row = blockIdx.x;               // b*256 + y
    const int b = row >> 8, y = row & 255;
#pragma unroll 8
    for (int c = 0; c < 64; ++c)
        tile[xx * 70 + c] = f2hs(x[((size_t)(b * 64 + c) << 16) + (y << 8) + xx]);
    int i = blockIdx.x * 256 + threadIdx.x;
    if (i < 64 * 576) {
        int o = i / 576, k = i - o * 576, t = k >> 6, c = k & 63;
        int kb = k >> 3, j = k & 7;
        int src = (o * 64 + c) * 9 + t;
        int dst = (kb * 64 + o) * 8 + j;
        wt_dcn[dst] = f2hs(w_dcn[src]);
        wt_h[dst]   = f2bf(w_h[src]);
        wt_w[dst]   = f2bf(w_w[src]);
        if (o < 32) wt_om[(kb * 32 + o) * 8 + j] = (o < 27) ? f2hs(w_om[src]) : (short)0;
        if (o == 0) w3t[k] = w3[c * 9 + t];
    }
    __syncthreads();
    short* op = xcl + ((row << 8) + xx) * 64;
    const int* tp = (const int*)&tile[xx * 70];      // 4B-aligned (140B row stride)
#pragma unroll
    for (int j = 0; j < 8; ++j) {
        int4 v;
        v.x = tp[j * 4 + 0]; v.y = tp[j * 4 + 1];
        v.z = tp[j * 4 + 2]; v.w = tp[j * 4 + 3];
        *(int4*)(op + j * 8) = v;                    // 16B coalesced store
    }
}

#define XPS 72   // LDS pixel stride (shorts): 144B, 16B-aligned

// ---------- FUSED om-conv + modulated deformable conv + BN1 + ReLU ----------
__global__ __launch_bounds__(256) __attribute__((amdgpu_waves_per_eu(2, 4)))
void k_dcn_mfma(const short* __restrict__ xcl,
        const short* __restrict__ wom, const float* __restrict__ b_om,
        const short* __restrict__ wt,
        const float* __restrict__ bias,
        const float* __restrict__ gg, const float* __restrict__ be,
        const float* __restrict__ mu, const float* __restrict__ var,
        short* __restrict__ out_cl) {
    __shared__ short xt[256 * XPS];                 // 36,864 B
    __shared__ _Float16 om_lds[64 * 32];            //  4,096 B
    const int lane = threadIdx.x & 63, wave = threadIdx.x >> 6;
    const int quad = lane >> 4, l16 = lane & 15;
    const int band = blockIdx.x & 7, idx = blockIdx.x >> 3;
    const int tr = band * 8 + (idx >> 5), tc = idx & 31;
    const int b = tr >> 5;
    const int ty0 = (tr & 31) * 8, tx0 = tc * 8;
    const int base = b << 16;
    const int hy0 = ty0 - 4, hx0 = tx0 - 4;
    // ---- stage 16x16 halo (clamped) ----
    {
        const int p = threadIdx.x;
        const int sy = min(max(hy0 + (p >> 4), 0), 255);
        const int sx = min(max(hx0 + (p & 15), 0), 255);
        const short* src = xcl + (size_t)((base + sy * 256 + sx) * 64);
        short* dst = &xt[p * XPS];
#pragma unroll
        for (int j = 0; j < 8; ++j)
            *(bf16x8*)(dst + j * 8) = *(const bf16x8*)(src + j * 8);
    }
    __syncthreads();

    const int lp = wave * 16 + l16;        // tile-local pixel (A-row m=l16)
    const int pyy = lp >> 3, pxx = lp & 7;
    const int y = ty0 + pyy, x = tx0 + pxx;

    // ---- phase 1: om conv for this tile (zero-OOB taps) ----
    {
        f32x4 oacc[2];
        oacc[0] = (f32x4){0,0,0,0}; oacc[1] = (f32x4){0,0,0,0};
        auto loadOB = [&](int s, f16x8* Bv) {
            const int kb = s * 4 + quad;
#pragma unroll
            for (int g = 0; g < 2; ++g)
                Bv[g] = *(const f16x8*)(wom + (kb * 32 + g * 16 + l16) * 8);
        };
        f16x8 OB[2][2];
        loadOB(0, OB[0]);
#pragma unroll
        for (int s = 0; s < 18; ++s) {
            if (s < 17) loadOB(s + 1, OB[(s + 1) & 1]);
            const int t = s >> 1, c0 = (s & 1) * 32;
            const int dy = t / 3 - 1, dx = t % 3 - 1;
            f16x8 av = *(const f16x8*)&xt[((pyy + 4 + dy) * 16 + (pxx + 4 + dx)) * XPS + c0 + quad * 8];
            bool ok = ((unsigned)(y + dy) < 256u) && ((unsigned)(x + dx) < 256u);
            if (!ok) { f16x8 z = {0,0,0,0,0,0,0,0}; av = z; }
#pragma unroll
            for (int g = 0; g < 2; ++g)
                oacc[g] = __builtin_amdgcn_mfma_f32_16x16x32_f16(av, OB[s & 1][g], oacc[g], 0, 0, 0);
        }
#pragma unroll
        for (int g = 0; g < 2; ++g) {
            int o = g * 16 + l16;
            if (o < 27) {
                float bo = b_om[o];
#pragma unroll
                for (int r = 0; r < 4; ++r) {
                    float v = oacc[g][r] + bo;
                    if (o >= 18) v = 1.f / (1.f + expf(-v));     // sigmoid(mask)
                    om_lds[(wave * 16 + quad * 4 + r) * 32 + o] = (_Float16)v;
                }
            }
        }
    }
    __syncthreads();

    // ---- phase 2: deformable conv, branchless, all-LDS gather, B double-buffer ----
    f32x4 acc[4];
#pragma unroll
    for (int i = 0; i < 4; ++i) acc[i] = (f32x4){0,0,0,0};

    _Float16 omh[28];
    *(f16x8*)&omh[0]  = *(const f16x8*)&om_lds[lp * 32];
    *(f16x8*)&omh[8]  = *(const f16x8*)&om_lds[lp * 32 + 8];
    *(f16x8*)&omh[16] = *(const f16x8*)&om_lds[lp * 32 + 16];
    *(f16x4*)&omh[24] = *(const f16x4*)&om_lds[lp * 32 + 24];

    f16x8 BR0[2][4], BR1[2][4];
    auto loadBt = [&](int t, f16x8 B[2][4]) {
#pragma unroll
        for (int h = 0; h < 2; ++h) {
            const int kb = t * 8 + h * 4 + quad;
#pragma unroll
            for (int g = 0; g < 4; ++g)
                B[h][g] = *(const f16x8*)(wt + (kb * 64 + g * 16 + l16) * 8);
        }
    };
    loadBt(0, BR0);

#pragma unroll
    for (int t = 0; t < 9; ++t) {
        f16x8 (*Bc)[4] = (t & 1) ? BR1 : BR0;
        f16x8 (*Bn)[4] = (t & 1) ? BR0 : BR1;
        if (t < 8) loadBt(t + 1, Bn);

        const int ky = t / 3 - 1, kx = t % 3 - 1;
        float o1 = (float)omh[t], o2 = (float)omh[9 + t], m = (float)omh[18 + t];
        float py = (float)(y + ky) + o1;
        float px = (float)(x + kx) + o2;
        float y0f = floorf(py), x0f = floorf(px);
        float wy1 = py - y0f, wx1 = px - x0f;
        int y0 = (int)y0f, xi0 = (int)x0f, y1 = y0 + 1, xi1 = xi0 + 1;
        float w00 = (1.f - wy1) * (1.f - wx1) * m;
        float w01 = (1.f - wy1) * wx1 * m;
        float w10 = wy1 * (1.f - wx1) * m;
        float w11 = wy1 * wx1 * m;
        if (!((unsigned)y0  < 256u)) { w00 = 0.f; w01 = 0.f; }
        if (!((unsigned)y1  < 256u)) { w10 = 0.f; w11 = 0.f; }
        if (!((unsigned)xi0 < 256u)) { w00 = 0.f; w10 = 0.f; }
        if (!((unsigned)xi1 < 256u)) { w01 = 0.f; w11 = 0.f; }
        int cy0 = min(max(y0, 0), 255), cy1 = min(max(y1, 0), 255);
        int cx0 = min(max(xi0, 0), 255), cx1 = min(max(xi1, 0), 255);
        int iy0 = cy0 - hy0, iy1 = cy1 - hy0;
        int ix0 = cx0 - hx0, ix1 = cx1 - hx0;
        if (!((unsigned)iy0 < 16u)) { w00 = 0.f; w01 = 0.f; iy0 = min(max(iy0, 0), 15); }
        if (!((unsigned)iy1 < 16u)) { w10 = 0.f; w11 = 0.f; iy1 = min(max(iy1, 0), 15); }
        if (!((unsigned)ix0 < 16u)) { w00 = 0.f; w10 = 0.f; ix0 = min(max(ix0, 0), 15); }
        if (!((unsigned)ix1 < 16u)) { w01 = 0.f; w11 = 0.f; ix1 = min(max(ix1, 0), 15); }

        const int p00 = (iy0 * 16 + ix0) * XPS, p01 = (iy0 * 16 + ix1) * XPS;
        const int p10 = (iy1 * 16 + ix0) * XPS, p11 = (iy1 * 16 + ix1) * XPS;
        f16x8 C[2][4];
#pragma unroll
        for (int h = 0; h < 2; ++h) {
            const int cb = h * 32 + quad * 8;
            C[h][0] = *(const f16x8*)&xt[p00 + cb];
            C[h][1] = *(const f16x8*)&xt[p01 + cb];
            C[h][2] = *(const f16x8*)&xt[p10 + cb];
            C[h][3] = *(const f16x8*)&xt[p11 + cb];
        }
        const _Float16 h00 = (_Float16)w00, h01 = (_Float16)w01;
        const _Float16 h10 = (_Float16)w10, h11 = (_Float16)w11;
        const f16x2 W00 = {h00, h00}, W01 = {h01, h01};
        const f16x2 W10 = {h10, h10}, W11 = {h11, h11};
#pragma unroll
        for (int h = 0; h < 2; ++h) {
            const f16x2* c0 = (const f16x2*)&C[h][0];
            const f16x2* c1 = (const f16x2*)&C[h][1];
            const f16x2* c2 = (const f16x2*)&C[h][2];
            const f16x2* c3 = (const f16x2*)&C[h][3];
            f16x8 av;
            f16x2* avp = (f16x2*)&av;
#pragma unroll
            for (int d = 0; d < 4; ++d) {
                f16x2 s = c0[d] * W00;
                s = __builtin_elementwise_fma(c1[d], W01, s);
                s = __builtin_elementwise_fma(c2[d], W10, s);
                s = __builtin_elementwise_fma(c3[d], W11, s);
                avp[d] = s;
            }
#pragma unroll
            for (int g = 0; g < 4; ++g)
                acc[g] = __builtin_amdgcn_mfma_f32_16x16x32_f16(av, Bc[h][g], acc[g], 0, 0, 0);
        }
    }
#pragma unroll
    for (int g = 0; g < 4; ++g) {
        int o = g * 16 + l16;
        float sc = gg[o] * rsqrtf(var[o] + 1e-5f);
        float off = (bias[o] - mu[o]) * sc + be[o];
#pragma unroll
        for (int r = 0; r < 4; ++r) {
            int mm = quad * 4 + r;
            int pix = base + ((ty0 + wave * 2 + (mm >> 3)) << 8) + tx0 + (mm & 7);
            float v = acc[g][r] * sc + off;
            out_cl[(size_t)pix * 64 + o] = f2bf(fmaxf(v, 0.f));
        }
    }
}

// ---------- dilated conv (dil=2 pad=2): 16x16 tile + 20x20 halo, 512 thr (r6 form) ----------
__global__ __launch_bounds__(512) __attribute__((amdgpu_waves_per_eu(2, 4)))
void k_conv_mfma(const short* __restrict__ in_cl,
        const short* __restrict__ wt, const float* __restrict__ bias,
        const float* __restrict__ gg, const float* __restrict__ be,
        const float* __restrict__ mu, const float* __restrict__ var,
        short* __restrict__ out_cl) {
    __shared__ short xt[400 * XPS];                  // 57.6 KB
    const int lane = threadIdx.x & 63, wave = threadIdx.x >> 6;   // wave 0..7
    const int quad = lane >> 4, l16 = lane & 15;
    const int tIdx = (blockIdx.x & 7) * 64 + (blockIdx.x >> 3);   // 512 blocks
    const int tr = tIdx >> 4, tc = tIdx & 15;
    const int b = tr >> 4;
    const int ty0 = (tr & 15) * 16, tx0 = tc * 16;
    const int base = b << 16;
    for (int i = threadIdx.x; i < 400 * 8; i += 512) {
        const int p = i >> 3, j = i & 7;
        const int sy = ty0 - 2 + p / 20, sx = tx0 - 2 + p % 20;
        bf16x8 v = {0,0,0,0,0,0,0,0};
        if (((unsigned)sy < 256u) && ((unsigned)sx < 256u))
            v = *(const bf16x8*)(in_cl + (size_t)((base + sy * 256 + sx) * 64 + j * 8));
        *(bf16x8*)(&xt[p * XPS + j * 8]) = v;
    }
    __syncthreads();
    const int ly = wave * 2;                 // rows ly, ly+1
    f32x4 acc[2][4];
#pragma unroll
    for (int h = 0; h < 2; ++h)
#pragma unroll
        for (int g = 0; g < 4; ++g) acc[h][g] = (f32x4){0,0,0,0};

    auto loadB = [&](int s, bf16x8* Bv) {
        const int kb = s * 4 + quad;
#pragma unroll
        for (int g = 0; g < 4; ++g)
            Bv[g] = *(const bf16x8*)(wt + (kb * 64 + g * 16 + l16) * 8);
    };
    bf16x8 B[3][4];
    loadB(0, B[0]);
    loadB(1, B[1]);
#pragma unroll
    for (int s = 0; s < 18; ++s) {
        if (s + 2 < 18) loadB(s + 2, B[(s + 2) % 3]);
        const int t = s >> 1, c0 = (s & 1) * 32;
        const int dy = (t / 3 - 1) * 2, dx = (t % 3 - 1) * 2;
        const int cidx = c0 + quad * 8;
        bf16x8 a0 = *(const bf16x8*)&xt[((ly + 2 + dy) * 20 + (l16 + 2 + dx)) * XPS + cidx];
        bf16x8 a1 = *(const bf16x8*)&xt[((ly + 3 + dy) * 20 + (l16 + 2 + dx)) * XPS + cidx];
#pragma unroll
        for (int g = 0; g < 4; ++g) {
            acc[0][g] = __builtin_amdgcn_mfma_f32_16x16x32_bf16(a0, B[s % 3][g], acc[0][g], 0, 0, 0);
            acc[1][g] = __builtin_amdgcn_mfma_f32_16x16x32_bf16(a1, B[s % 3][g], acc[1][g], 0, 0, 0);
        }
    }
#pragma unroll
    for (int h = 0; h < 2; ++h)
#pragma unroll
    for (int g = 0; g < 4; ++g) {
        int o = g * 16 + l16;
        float sc = gg[o] * rsqrtf(var[o] + 1e-5f);
        float off = (bias[o] - mu[o]) * sc + be[o];
#pragma unroll
        for (int r = 0; r < 4; ++r) {
            int pix = base + ((ty0 + ly + h) << 8) + tx0 + quad * 4 + r;
            float v = acc[h][g][r] * sc + off;
            out_cl[(size_t)pix * 64 + o] = f2bf(fmaxf(v, 0.f));
        }
    }
}

// ---------- final 3x3 conv (pad=1) + sigmoid + clip : 16x16 tile + 18x18 halo ----------
__global__ __launch_bounds__(256) void k_final(const short* __restrict__ h_cl,
        const float* __restrict__ w3t, const float* __restrict__ b3,
        float* __restrict__ out) {
    __shared__ short xt[324 * XPS];                  // 46.7 KB
    const int tIdx = (blockIdx.x & 7) * 64 + (blockIdx.x >> 3);   // 512 blocks
    const int tr = tIdx >> 4, tc = tIdx & 15;
    const int b = tr >> 4;
    const int ty0 = (tr & 15) * 16, tx0 = tc * 16;
    const int base = b << 16;
    for (int i = threadIdx.x; i < 324 * 8; i += 256) {
        const int p = i >> 3, j = i & 7;
        const int sy = ty0 - 1 + p / 18, sx = tx0 - 1 + p % 18;
        bf16x8 v = {0,0,0,0,0,0,0,0};
        if (((unsigned)sy < 256u) && ((unsigned)sx < 256u))
            v = *(const bf16x8*)(h_cl + (size_t)((base + sy * 256 + sx) * 64 + j * 8));
        *(bf16x8*)(&xt[p * XPS + j * 8]) = v;
    }
    __syncthreads();
    const int ly = threadIdx.x >> 4, lx = threadIdx.x & 15;
    float a0 = 0.f, a1 = 0.f, a2 = 0.f, a3 = 0.f;
#pragma unroll
    for (int t = 0; t < 9; ++t) {
        const int hidx = (ly + 1 + t / 3 - 1) * 18 + (lx + 1 + t % 3 - 1);
        const short* hp = &xt[hidx * XPS];
        const float* wp = w3t + t * 64;
#pragma unroll
        for (int j = 0; j < 64; j += 32) {
            bf16x8 v0 = *(const bf16x8*)(hp + j);
            bf16x8 v1 = *(const bf16x8*)(hp + j + 8);
            bf16x8 v2 = *(const bf16x8*)(hp + j + 16);
            bf16x8 v3 = *(const bf16x8*)(hp + j + 24);
#pragma unroll
            for (int e = 0; e < 8; ++e) {
                a0 = fmaf(bf2f(v0[e]), wp[j + e], a0);
                a1 = fmaf(bf2f(v1[e]), wp[j + 8 + e], a1);
                a2 = fmaf(bf2f(v2[e]), wp[j + 16 + e], a2);
                a3 = fmaf(bf2f(v3[e]), wp[j + 24 + e], a3);
            }
        }
    }
    float acc = (a0 + a1) + (a2 + a3);
    float s = 1.f / (1.f + expf(-(acc + b3[0])));
    out[base + ((ty0 + ly) << 8) + tx0 + lx] = fminf(fmaxf(s, 1e-4f), 1.f - 1e-4f);
}

extern "C" void kernel_launch(void* const* d_in, const int* in_sizes, int n_in,
                              void* d_out, int out_size, void* d_ws, size_t ws_size,
                              hipStream_t stream) {
    const float* x     = (const float*)d_in[0];
    const float* w_om  = (const float*)d_in[1];
    const float* b_om  = (const float*)d_in[2];
    const float* w_dcn = (const float*)d_in[3];
    const float* b_dcn = (const float*)d_in[4];
    const float* bn1g = (const float*)d_in[5],  *bn1b = (const float*)d_in[6];
    const float* bn1m = (const float*)d_in[7],  *bn1v = (const float*)d_in[8];
    const float* bn2g = (const float*)d_in[9],  *bn2b = (const float*)d_in[10];
    const float* bn2m = (const float*)d_in[11], *bn2v = (const float*)d_in[12];
    const float* bn3g = (const float*)d_in[13], *bn3b = (const float*)d_in[14];
    const float* bn3m = (const float*)d_in[15], *bn3v = (const float*)d_in[16];
    const float* w_h = (const float*)d_in[17], *b_h = (const float*)d_in[18];
    const float* w_w = (const float*)d_in[19], *b_w = (const float*)d_in[20];
    const float* w3  = (const float*)d_in[21], *b3  = (const float*)d_in[22];
    float* outp = (float*)d_out;

    // workspace layout
    char* ws = (char*)d_ws;
    short* xcl   = (short*)ws;                         // fp16 16.78 MB
    short* h1    = xcl + (size_t)NPX * 64;
    short* h2    = h1 + (size_t)NPX * 64;
    short* wt_om  = h2 + (size_t)NPX * 64;             // 32*576 fp16
    short* wt_dcn = wt_om  + 32 * 576;                 // 64*576 fp16
    short* wt_h   = wt_dcn + 64 * 576;                 // bf16
    short* wt_w   = wt_h   + 64 * 576;                 // bf16
    float* w3t    = (float*)(wt_w + 64 * 576);         // 576 fp32

    dim3 blk(256);
    k_x2cl<<<512, blk, 0, stream>>>(x, xcl, w_om, w_dcn, w_h, w_w, w3,
                                    wt_om, wt_dcn, wt_h, wt_w, w3t);
    k_dcn_mfma<<<NPX / 64, blk, 0, stream>>>(xcl, wt_om, b_om, wt_dcn, b_dcn,
                                             bn1g, bn1b, bn1m, bn1v, h1);
    k_conv_mfma<<<512, dim3(512), 0, stream>>>(h1, wt_h, b_h, bn2g, bn2b, bn2m, bn2v, h2);
    k_conv_mfma<<<512, dim3(512), 0, stream>>>(h2, wt_w, b_w, bn3g, bn3b, bn3m, bn3v, h1);
    k_final<<<512, blk, 0, stream>>>(h1, w3t, b3, outp);
}